// Round 1
// baseline (342.251 us; speedup 1.0000x reference)
//
#include <hip/hip_runtime.h>

// Problem constants (B,C,H,W = 2,64,48,48; nh=8 -> d=8, L=2304)
#define LL   2304
#define CCH  64
#define NBAT 2
#define NHD  8

static constexpr float QSCALE = 0.35355339059327373f;  // 8^-0.5
static constexpr float LOG2E  = 1.4426950408889634f;

__device__ __forceinline__ float2 f2mul(float ax, float ay, float2 b) {
    return make_float2(ax * b.x, ay * b.y);
}
__device__ __forceinline__ float2 f2fma(float ax, float ay, float2 b, float2 c) {
    return make_float2(fmaf(ax, b.x, c.x), fmaf(ay, b.y, c.y));
}

// ---------------------------------------------------------------------------
// Kernel 1: q/k/v = conv1x1(x, W*, b*).  Writes scaled q to d_out (2nd output),
// and Q',K,V as row-major [bh][l][8] to workspace.  Q' = q * (d^-0.5 * log2e).
// grid (36 ltiles of 64, B, 3 mats), block 256 = 64 l x 4 cgroups of 16 c.
// ---------------------------------------------------------------------------
__global__ __launch_bounds__(256) void k_qkv(
    const float* __restrict__ x,
    const float* __restrict__ Wq, const float* __restrict__ bq,
    const float* __restrict__ Wk, const float* __restrict__ bk,
    const float* __restrict__ Wv, const float* __restrict__ bv,
    float* __restrict__ qout,  // d_out + 294912, layout [B][C][L]
    float* __restrict__ Qt, float* __restrict__ Kt, float* __restrict__ Vt)
{
    __shared__ float xs[64][64];
    __shared__ float wsm[64][64];
    const int t   = threadIdx.x;
    const int l0  = blockIdx.x * 64;
    const int b   = blockIdx.y;
    const int mat = blockIdx.z;
    const float* W    = (mat == 0) ? Wq : (mat == 1 ? Wk : Wv);
    const float* bias = (mat == 0) ? bq : (mat == 1 ? bk : bv);
    const float* xb = x + (long)b * CCH * LL;

    // stage x tile [64c][64l] and W [64][64] (16KB each)
    #pragma unroll
    for (int p = 0; p < 4; ++p) {
        int flat = (p * 256 + t) * 4;
        int c = flat >> 6, l = flat & 63;
        *(float4*)&xs[c][l]  = *(const float4*)&xb[(long)c * LL + l0 + l];
        *(float4*)&wsm[c][l] = *(const float4*)&W[flat];
    }
    __syncthreads();

    const int l  = t & 63;
    const int cg = t >> 6;  // 0..3
    float acc[16];
    #pragma unroll
    for (int j = 0; j < 16; ++j) acc[j] = 0.f;
    for (int cp = 0; cp < 64; ++cp) {
        float xv = xs[cp][l];
        #pragma unroll
        for (int j = 0; j < 16; ++j) acc[j] = fmaf(wsm[cg * 16 + j][cp], xv, acc[j]);
    }
    #pragma unroll
    for (int j = 0; j < 16; ++j) {
        int c = cg * 16 + j;
        float v = acc[j] + bias[c];
        int h = c >> 3, dd = c & 7;
        long tofs = ((long)((b * NHD + h) * LL + (l0 + l))) * 8 + dd;
        if (mat == 0) {
            float qv = v * QSCALE;
            qout[(long)(b * CCH + c) * LL + l0 + l] = qv;
            Qt[tofs] = qv * LOG2E;
        } else if (mat == 1) {
            Kt[tofs] = v;
        } else {
            Vt[tofs] = v;
        }
    }
}

// ---------------------------------------------------------------------------
// Kernel 2: D[k] = sum_q 2^(Q'[q].K[k]); then fold V[k][:] *= 1/D[k] in place.
// grid (72 ktiles of 32, 16 bh), block 256 = 32 k x 8 q-chunks of 288.
// ---------------------------------------------------------------------------
__global__ __launch_bounds__(256) void k_denom(
    const float* __restrict__ Qt, const float* __restrict__ Kt,
    float* __restrict__ Vt)
{
    const int t  = threadIdx.x;
    const int bh = blockIdx.y;
    const int k0 = blockIdx.x * 32;
    const int kk = t & 31, qc = t >> 5;

    const float4* krow = (const float4*)(Kt + ((long)bh * LL + k0 + kk) * 8);
    float4 ka = krow[0], kb = krow[1];

    float D = 0.f;
    const float4* qp = (const float4*)(Qt + ((long)bh * LL + qc * 288) * 8);
    #pragma unroll 2
    for (int i = 0; i < 288; ++i) {
        float4 qa = qp[2 * i], qv = qp[2 * i + 1];
        float2 s2 = f2mul(qa.x, qa.y, make_float2(ka.x, ka.y));
        s2 = f2fma(qa.z, qa.w, make_float2(ka.z, ka.w), s2);
        s2 = f2fma(qv.x, qv.y, make_float2(kb.x, kb.y), s2);
        s2 = f2fma(qv.z, qv.w, make_float2(kb.z, kb.w), s2);
        D += __builtin_amdgcn_exp2f(s2.x + s2.y);
    }

    __shared__ float Dp[8][32];
    __shared__ float Dr[32];
    Dp[qc][kk] = D;
    __syncthreads();
    if (t < 32) {
        float s = 0.f;
        #pragma unroll
        for (int j = 0; j < 8; ++j) s += Dp[j][t];
        Dr[t] = 1.0f / s;
    }
    __syncthreads();
    // V' = V * (1/D): 32k x 8c = 256 elements, one per thread
    const int kk2 = t >> 3, c = t & 7;
    long vofs = ((long)bh * LL + k0 + kk2) * 8 + c;
    Vt[vofs] *= Dr[kk2];
}

// ---------------------------------------------------------------------------
// Kernel 3: o[c][q] = sum_k V'[k][c] * 2^(Q'[q].K[k]).  Writes ot[b][cv][l].
// grid (72 qtiles of 32, 16 bh), block 256 = 32 q x 8 k-chunks of 288.
// ---------------------------------------------------------------------------
__global__ __launch_bounds__(256) void k_av(
    const float* __restrict__ Qt, const float* __restrict__ Kt,
    const float* __restrict__ Vp, float* __restrict__ ot)
{
    const int t  = threadIdx.x;
    const int bh = blockIdx.y;
    const int b = bh >> 3, h = bh & 7;
    const int q0 = blockIdx.x * 32;
    const int qq = t & 31, kc = t >> 5;

    const float4* qrow = (const float4*)(Qt + ((long)bh * LL + q0 + qq) * 8);
    float4 qa = qrow[0], qb = qrow[1];

    float2 o0 = make_float2(0.f, 0.f), o1 = o0, o2 = o0, o3 = o0;
    const float4* kp = (const float4*)(Kt + ((long)bh * LL + kc * 288) * 8);
    const float4* vp = (const float4*)(Vp + ((long)bh * LL + kc * 288) * 8);
    #pragma unroll 2
    for (int i = 0; i < 288; ++i) {
        float4 ka = kp[2 * i], kb = kp[2 * i + 1];
        float4 va = vp[2 * i], vb = vp[2 * i + 1];
        float2 s2 = f2mul(ka.x, ka.y, make_float2(qa.x, qa.y));
        s2 = f2fma(ka.z, ka.w, make_float2(qa.z, qa.w), s2);
        s2 = f2fma(kb.x, kb.y, make_float2(qb.x, qb.y), s2);
        s2 = f2fma(kb.z, kb.w, make_float2(qb.z, qb.w), s2);
        float e = __builtin_amdgcn_exp2f(s2.x + s2.y);
        float2 e2 = make_float2(e, e);
        o0 = f2fma(va.x, va.y, e2, o0);
        o1 = f2fma(va.z, va.w, e2, o1);
        o2 = f2fma(vb.x, vb.y, e2, o2);
        o3 = f2fma(vb.z, vb.w, e2, o3);
    }

    __shared__ float2 Op[8][32][4];
    Op[kc][qq][0] = o0; Op[kc][qq][1] = o1;
    Op[kc][qq][2] = o2; Op[kc][qq][3] = o3;
    __syncthreads();
    if (t < 128) {
        int q2 = t & 31, c2 = t >> 5;  // c2 in 0..3
        float sx = 0.f, sy = 0.f;
        #pragma unroll
        for (int j = 0; j < 8; ++j) {
            float2 v = Op[j][q2][c2];
            sx += v.x; sy += v.y;
        }
        int cv0 = h * 8 + c2 * 2;
        ot[((long)b * CCH + cv0) * LL + q0 + q2]     = sx;
        ot[((long)b * CCH + cv0 + 1) * LL + q0 + q2] = sy;
    }
}

// ---------------------------------------------------------------------------
// Kernel 4: out[b][co][l] = sum_cv Wo[co][cv] * ot[b][cv][l] + bo[co]
// grid (72 ltiles of 32, B), block 256 = 32 l x 8 cgroups of 8 co.
// ---------------------------------------------------------------------------
__global__ __launch_bounds__(256) void k_out(
    const float* __restrict__ ot, const float* __restrict__ Wo,
    const float* __restrict__ bo, float* __restrict__ out)
{
    __shared__ float os[64][32];
    __shared__ float wsm[64][64];
    const int t  = threadIdx.x;
    const int l0 = blockIdx.x * 32;
    const int b  = blockIdx.y;
    const float* ob = ot + (long)b * CCH * LL;

    #pragma unroll
    for (int p = 0; p < 2; ++p) {
        int flat = (p * 256 + t) * 4;
        int cv = flat >> 5, l = flat & 31;
        *(float4*)&os[cv][l] = *(const float4*)&ob[(long)cv * LL + l0 + l];
    }
    #pragma unroll
    for (int p = 0; p < 4; ++p) {
        int flat = (p * 256 + t) * 4;
        int c = flat >> 6, l = flat & 63;
        *(float4*)&wsm[c][l] = *(const float4*)&Wo[flat];
    }
    __syncthreads();

    const int l  = t & 31;
    const int cg = t >> 5;  // 0..7
    float acc[8];
    #pragma unroll
    for (int j = 0; j < 8; ++j) acc[j] = 0.f;
    for (int cv = 0; cv < 64; ++cv) {
        float xv = os[cv][l];
        #pragma unroll
        for (int j = 0; j < 8; ++j) acc[j] = fmaf(wsm[cg * 8 + j][cv], xv, acc[j]);
    }
    #pragma unroll
    for (int j = 0; j < 8; ++j) {
        int co = cg * 8 + j;
        out[((long)b * CCH + co) * LL + l0 + l] = acc[j] + bo[co];
    }
}

// ---------------------------------------------------------------------------
extern "C" void kernel_launch(void* const* d_in, const int* in_sizes, int n_in,
                              void* d_out, int out_size, void* d_ws, size_t ws_size,
                              hipStream_t stream)
{
    const float* x  = (const float*)d_in[0];
    const float* Wq = (const float*)d_in[1];
    const float* bq = (const float*)d_in[2];
    const float* Wk = (const float*)d_in[3];
    const float* bk = (const float*)d_in[4];
    const float* Wv = (const float*)d_in[5];
    const float* bv = (const float*)d_in[6];
    const float* Wo = (const float*)d_in[7];
    const float* bo = (const float*)d_in[8];

    float* out  = (float*)d_out;          // [2][64][2304] = 294912 floats
    float* qout = out + 294912;           // second tuple output: scaled q

    float* wsf = (float*)d_ws;            // needs 4 x 294912 floats = 4.72 MB
    float* Qt = wsf;                      // [16][2304][8], pre-scaled by log2e*d^-0.5
    float* Kt = wsf + 294912;             // [16][2304][8]
    float* Vt = wsf + 589824;             // [16][2304][8] -> becomes V/D in k_denom
    float* ot = wsf + 884736;             // [2][64][2304]

    k_qkv  <<<dim3(36, 2, 3), 256, 0, stream>>>(x, Wq, bq, Wk, bk, Wv, bv, qout, Qt, Kt, Vt);
    k_denom<<<dim3(72, 16),   256, 0, stream>>>(Qt, Kt, Vt);
    k_av   <<<dim3(72, 16),   256, 0, stream>>>(Qt, Kt, Vt, ot);
    k_out  <<<dim3(72, 2),    256, 0, stream>>>(ot, Wo, bo, out);
}

// Round 2
// 195.022 us; speedup vs baseline: 1.7549x; 1.7549x over previous
//
#include <hip/hip_runtime.h>

// Problem constants (B,C,H,W = 2,64,48,48; nh=8 -> d=8, L=2304)
#define LL   2304
#define CCH  64
#define NBAT 2
#define NHD  8

static constexpr float QSCALE = 0.35355339059327373f;  // 8^-0.5
static constexpr float LOG2E  = 1.4426950408889634f;

__device__ __forceinline__ float2 f2mul(float ax, float ay, float2 b) {
    return make_float2(ax * b.x, ay * b.y);
}
__device__ __forceinline__ float2 f2fma(float ax, float ay, float2 b, float2 c) {
    return make_float2(fmaf(ax, b.x, c.x), fmaf(ay, b.y, c.y));
}

// ---------------------------------------------------------------------------
// Kernel 1: q/k/v = conv1x1(x, W*, b*).  Writes scaled q to d_out (2nd output),
// and Q',K,V as row-major [bh][l][8] to workspace.  Q' = q * (d^-0.5 * log2e).
// grid (36 ltiles of 64, B, 3 mats), block 256 = 64 l x 4 cgroups of 16 c.
// ---------------------------------------------------------------------------
__global__ __launch_bounds__(256) void k_qkv(
    const float* __restrict__ x,
    const float* __restrict__ Wq, const float* __restrict__ bq,
    const float* __restrict__ Wk, const float* __restrict__ bk,
    const float* __restrict__ Wv, const float* __restrict__ bv,
    float* __restrict__ qout,  // d_out + 294912, layout [B][C][L]
    float* __restrict__ Qt, float* __restrict__ Kt, float* __restrict__ Vt)
{
    __shared__ float xs[64][64];
    __shared__ float wsm[64][64];
    const int t   = threadIdx.x;
    const int l0  = blockIdx.x * 64;
    const int b   = blockIdx.y;
    const int mat = blockIdx.z;
    const float* W    = (mat == 0) ? Wq : (mat == 1 ? Wk : Wv);
    const float* bias = (mat == 0) ? bq : (mat == 1 ? bk : bv);
    const float* xb = x + (long)b * CCH * LL;

    #pragma unroll
    for (int p = 0; p < 4; ++p) {
        int flat = (p * 256 + t) * 4;
        int c = flat >> 6, l = flat & 63;
        *(float4*)&xs[c][l]  = *(const float4*)&xb[(long)c * LL + l0 + l];
        *(float4*)&wsm[c][l] = *(const float4*)&W[flat];
    }
    __syncthreads();

    const int l  = t & 63;
    const int cg = t >> 6;  // 0..3
    float acc[16];
    #pragma unroll
    for (int j = 0; j < 16; ++j) acc[j] = 0.f;
    for (int cp = 0; cp < 64; ++cp) {
        float xv = xs[cp][l];
        #pragma unroll
        for (int j = 0; j < 16; ++j) acc[j] = fmaf(wsm[cg * 16 + j][cp], xv, acc[j]);
    }
    #pragma unroll
    for (int j = 0; j < 16; ++j) {
        int c = cg * 16 + j;
        float v = acc[j] + bias[c];
        int h = c >> 3, dd = c & 7;
        long tofs = ((long)((b * NHD + h) * LL + (l0 + l))) * 8 + dd;
        if (mat == 0) {
            float qv = v * QSCALE;
            qout[(long)(b * CCH + c) * LL + l0 + l] = qv;
            Qt[tofs] = qv * LOG2E;
        } else if (mat == 1) {
            Kt[tofs] = v;
        } else {
            Vt[tofs] = v;
        }
    }
}

// ---------------------------------------------------------------------------
// Kernel 2: rcpD[bh][k] = 1 / sum_q 2^(Q'[q].K[k]).
// grid (36 ktiles of 64, 16 bh), block 256 = 64 k x 4 q-subranges.
// Q staged through LDS in 64-row chunks with register prefetch.
// ---------------------------------------------------------------------------
__global__ __launch_bounds__(256) void k_denom(
    const float* __restrict__ Qt, const float* __restrict__ Kt,
    float* __restrict__ rcpD)
{
    __shared__ float lQ[64][8];   // 2KB chunk of Q rows
    __shared__ float Dp[4][64];
    const int t  = threadIdx.x;
    const int bh = blockIdx.y;
    const int k0 = blockIdx.x * 64;
    const int kk = t & 63, qs = t >> 6;

    const float4* krow = (const float4*)(Kt + ((long)bh * LL + k0 + kk) * 8);
    float4 ka = krow[0], kb = krow[1];

    const float4* qbase = (const float4*)(Qt + (long)bh * LL * 8);
    float4 pre;
    if (t < 128) pre = qbase[t];   // chunk 0 (128 float4 = 64 rows)

    float D = 0.f;
    for (int ch = 0; ch < 36; ++ch) {
        __syncthreads();                       // prior compute done, lQ free
        if (t < 128) ((float4*)lQ)[t] = pre;
        __syncthreads();                       // chunk visible
        if (t < 128 && ch + 1 < 36) pre = qbase[(ch + 1) * 128 + t];
        #pragma unroll
        for (int jj = 0; jj < 16; ++jj) {
            int j = qs * 16 + jj;              // wave-uniform -> LDS broadcast
            float4 qa = *(const float4*)&lQ[j][0];
            float4 qb = *(const float4*)&lQ[j][4];
            float2 s2 = f2mul(qa.x, qa.y, make_float2(ka.x, ka.y));
            s2 = f2fma(qa.z, qa.w, make_float2(ka.z, ka.w), s2);
            s2 = f2fma(qb.x, qb.y, make_float2(kb.x, kb.y), s2);
            s2 = f2fma(qb.z, qb.w, make_float2(kb.z, kb.w), s2);
            D += __builtin_amdgcn_exp2f(s2.x + s2.y);
        }
    }
    __syncthreads();
    Dp[qs][kk] = D;
    __syncthreads();
    if (t < 64) {
        float s = Dp[0][t] + Dp[1][t] + Dp[2][t] + Dp[3][t];
        rcpD[(long)bh * LL + k0 + t] = 1.0f / s;
    }
}

// ---------------------------------------------------------------------------
// Kernel 3: o[c][q] = sum_k V[k][c] * rcpD[k] * 2^(Q'[q].K[k]).
// grid (36 qtiles of 64, 16 bh), block 256 = 64 q x 4 k-subranges.
// K/V/rcpD staged through LDS in 64-key chunks with register prefetch.
// ---------------------------------------------------------------------------
__global__ __launch_bounds__(256) void k_av(
    const float* __restrict__ Qt, const float* __restrict__ Kt,
    const float* __restrict__ Vt, const float* __restrict__ rcpD,
    float* __restrict__ ot)
{
    __shared__ float lK[64][8];
    __shared__ float lV[64][8];
    __shared__ float lR[64];
    __shared__ float Op[4][64][9];   // pad 8->9: kill 4-way bank conflict
    const int t  = threadIdx.x;
    const int bh = blockIdx.y;
    const int b = bh >> 3, h = bh & 7;
    const int q0 = blockIdx.x * 64;
    const int qq = t & 63, ks = t >> 6;

    const float4* qrow = (const float4*)(Qt + ((long)bh * LL + q0 + qq) * 8);
    float4 qa = qrow[0], qb = qrow[1];

    const float4* kbase = (const float4*)(Kt + (long)bh * LL * 8);
    const float4* vbase = (const float4*)(Vt + (long)bh * LL * 8);
    const float4* rbase = (const float4*)(rcpD + (long)bh * LL);

    float4 pre  = (t < 128) ? kbase[t] : vbase[t - 128];
    float4 rpre;
    if (t < 16) rpre = rbase[t];

    float2 o0 = {0.f, 0.f}, o1 = o0, o2 = o0, o3 = o0;
    for (int ch = 0; ch < 36; ++ch) {
        __syncthreads();
        if (t < 128) ((float4*)lK)[t] = pre;
        else         ((float4*)lV)[t - 128] = pre;
        if (t < 16)  ((float4*)lR)[t] = rpre;
        __syncthreads();
        if (ch + 1 < 36) {
            pre = (t < 128) ? kbase[(ch + 1) * 128 + t]
                            : vbase[(ch + 1) * 128 + (t - 128)];
            if (t < 16) rpre = rbase[(ch + 1) * 16 + t];
        }
        #pragma unroll
        for (int jj = 0; jj < 16; ++jj) {
            int j = ks * 16 + jj;              // wave-uniform -> LDS broadcast
            float4 ka = *(const float4*)&lK[j][0];
            float4 kb = *(const float4*)&lK[j][4];
            float2 s2 = f2mul(ka.x, ka.y, make_float2(qa.x, qa.y));
            s2 = f2fma(ka.z, ka.w, make_float2(qa.z, qa.w), s2);
            s2 = f2fma(kb.x, kb.y, make_float2(qb.x, qb.y), s2);
            s2 = f2fma(kb.z, kb.w, make_float2(qb.z, qb.w), s2);
            float e = __builtin_amdgcn_exp2f(s2.x + s2.y) * lR[j];
            float4 va = *(const float4*)&lV[j][0];
            float4 vb = *(const float4*)&lV[j][4];
            float2 e2 = make_float2(e, e);
            o0 = f2fma(va.x, va.y, e2, o0);
            o1 = f2fma(va.z, va.w, e2, o1);
            o2 = f2fma(vb.x, vb.y, e2, o2);
            o3 = f2fma(vb.z, vb.w, e2, o3);
        }
    }
    __syncthreads();
    Op[ks][qq][0] = o0.x; Op[ks][qq][1] = o0.y;
    Op[ks][qq][2] = o1.x; Op[ks][qq][3] = o1.y;
    Op[ks][qq][4] = o2.x; Op[ks][qq][5] = o2.y;
    Op[ks][qq][6] = o3.x; Op[ks][qq][7] = o3.y;
    __syncthreads();
    {
        int q2 = t & 63, c0 = (t >> 6) * 2;
        float s0 = 0.f, s1 = 0.f;
        #pragma unroll
        for (int j2 = 0; j2 < 4; ++j2) {
            s0 += Op[j2][q2][c0];
            s1 += Op[j2][q2][c0 + 1];
        }
        ot[((long)b * CCH + h * 8 + c0) * LL + q0 + q2]     = s0;
        ot[((long)b * CCH + h * 8 + c0 + 1) * LL + q0 + q2] = s1;
    }
}

// ---------------------------------------------------------------------------
// Kernel 4: out[b][co][l] = sum_cv Wo[co][cv] * ot[b][cv][l] + bo[co]
// grid (72 ltiles of 32, B), block 256 = 32 l x 8 cgroups of 8 co.
// ---------------------------------------------------------------------------
__global__ __launch_bounds__(256) void k_out(
    const float* __restrict__ ot, const float* __restrict__ Wo,
    const float* __restrict__ bo, float* __restrict__ out)
{
    __shared__ float os[64][32];
    __shared__ float wsm[64][64];
    const int t  = threadIdx.x;
    const int l0 = blockIdx.x * 32;
    const int b  = blockIdx.y;
    const float* ob = ot + (long)b * CCH * LL;

    #pragma unroll
    for (int p = 0; p < 2; ++p) {
        int flat = (p * 256 + t) * 4;
        int cv = flat >> 5, l = flat & 31;
        *(float4*)&os[cv][l] = *(const float4*)&ob[(long)cv * LL + l0 + l];
    }
    #pragma unroll
    for (int p = 0; p < 4; ++p) {
        int flat = (p * 256 + t) * 4;
        int c = flat >> 6, l = flat & 63;
        *(float4*)&wsm[c][l] = *(const float4*)&Wo[flat];
    }
    __syncthreads();

    const int l  = t & 31;
    const int cg = t >> 5;  // 0..7
    float acc[8];
    #pragma unroll
    for (int j = 0; j < 8; ++j) acc[j] = 0.f;
    for (int cv = 0; cv < 64; ++cv) {
        float xv = os[cv][l];
        #pragma unroll
        for (int j = 0; j < 8; ++j) acc[j] = fmaf(wsm[cg * 8 + j][cv], xv, acc[j]);
    }
    #pragma unroll
    for (int j = 0; j < 8; ++j) {
        int co = cg * 8 + j;
        out[((long)b * CCH + co) * LL + l0 + l] = acc[j] + bo[co];
    }
}

// ---------------------------------------------------------------------------
extern "C" void kernel_launch(void* const* d_in, const int* in_sizes, int n_in,
                              void* d_out, int out_size, void* d_ws, size_t ws_size,
                              hipStream_t stream)
{
    const float* x  = (const float*)d_in[0];
    const float* Wq = (const float*)d_in[1];
    const float* bq = (const float*)d_in[2];
    const float* Wk = (const float*)d_in[3];
    const float* bk = (const float*)d_in[4];
    const float* Wv = (const float*)d_in[5];
    const float* bv = (const float*)d_in[6];
    const float* Wo = (const float*)d_in[7];
    const float* bo = (const float*)d_in[8];

    float* out  = (float*)d_out;          // [2][64][2304] = 294912 floats
    float* qout = out + 294912;           // second tuple output: scaled q

    float* wsf  = (float*)d_ws;           // 1,216,512 floats = 4.87 MB
    float* Qt   = wsf;                    // [16][2304][8], pre-scaled by log2e*d^-0.5
    float* Kt   = wsf + 294912;           // [16][2304][8]
    float* Vt   = wsf + 589824;           // [16][2304][8]
    float* rcpD = wsf + 884736;           // [16][2304]
    float* ot   = wsf + 921600;           // [2][64][2304]

    k_qkv  <<<dim3(36, 2, 3), 256, 0, stream>>>(x, Wq, bq, Wk, bk, Wv, bv, qout, Qt, Kt, Vt);
    k_denom<<<dim3(36, 16),   256, 0, stream>>>(Qt, Kt, rcpD);
    k_av   <<<dim3(36, 16),   256, 0, stream>>>(Qt, Kt, Vt, rcpD, ot);
    k_out  <<<dim3(72, 2),    256, 0, stream>>>(ot, Wo, bo, out);
}

// Round 3
// 161.240 us; speedup vs baseline: 2.1226x; 1.2095x over previous
//
#include <hip/hip_runtime.h>

// Problem constants (B,C,H,W = 2,64,48,48; nh=8 -> d=8, L=2304)
#define LL   2304
#define CCH  64
#define NHD  8

static constexpr float QSCALE = 0.35355339059327373f;  // 8^-0.5
static constexpr float LOG2E  = 1.4426950408889634f;

__device__ __forceinline__ float2 f2mul(float ax, float ay, float2 b) {
    return make_float2(ax * b.x, ay * b.y);
}
__device__ __forceinline__ float2 f2fma(float ax, float ay, float2 b, float2 c) {
    return make_float2(fmaf(ax, b.x, c.x), fmaf(ay, b.y, c.y));
}

// ---------------------------------------------------------------------------
// Kernel 1: q/k/v = conv1x1(x, W*, b*).  Writes scaled q to d_out (2nd output),
// and Q',K,V as row-major [bh][l][8] to workspace.  Q' = q * (d^-0.5 * log2e).
// grid (72 ltiles of 32, B, 3 mats), block 256 = 32 l x 8 cgroups of 8 c.
// ---------------------------------------------------------------------------
__global__ __launch_bounds__(256) void k_qkv(
    const float* __restrict__ x,
    const float* __restrict__ Wq, const float* __restrict__ bq,
    const float* __restrict__ Wk, const float* __restrict__ bk,
    const float* __restrict__ Wv, const float* __restrict__ bv,
    float* __restrict__ qout,  // d_out + 294912, layout [B][C][L]
    float* __restrict__ Qt, float* __restrict__ Kt, float* __restrict__ Vt)
{
    __shared__ float xs[64][32];
    __shared__ float wsm[64][64];
    const int t   = threadIdx.x;
    const int l0  = blockIdx.x * 32;
    const int b   = blockIdx.y;
    const int mat = blockIdx.z;
    const float* W    = (mat == 0) ? Wq : (mat == 1 ? Wk : Wv);
    const float* bias = (mat == 0) ? bq : (mat == 1 ? bk : bv);
    const float* xb = x + (long)b * CCH * LL;

    #pragma unroll
    for (int p = 0; p < 2; ++p) {
        int flat = (p * 256 + t) * 4;
        int c = flat >> 5, l = flat & 31;
        *(float4*)&xs[c][l] = *(const float4*)&xb[(long)c * LL + l0 + l];
    }
    #pragma unroll
    for (int p = 0; p < 4; ++p) {
        int flat = (p * 256 + t) * 4;
        int c = flat >> 6, l = flat & 63;
        *(float4*)&wsm[c][l] = *(const float4*)&W[flat];
    }
    __syncthreads();

    const int l  = t & 31;
    const int cg = t >> 5;  // 0..7
    float acc[8];
    #pragma unroll
    for (int j = 0; j < 8; ++j) acc[j] = 0.f;
    for (int cp = 0; cp < 64; ++cp) {
        float xv = xs[cp][l];
        #pragma unroll
        for (int j = 0; j < 8; ++j) acc[j] = fmaf(wsm[cg * 8 + j][cp], xv, acc[j]);
    }
    #pragma unroll
    for (int j = 0; j < 8; ++j) {
        int c = cg * 8 + j;
        float v = acc[j] + bias[c];
        int h = c >> 3, dd = c & 7;
        long tofs = ((long)((b * NHD + h) * LL + (l0 + l))) * 8 + dd;
        if (mat == 0) {
            float qv = v * QSCALE;
            qout[(long)(b * CCH + c) * LL + l0 + l] = qv;
            Qt[tofs] = qv * LOG2E;
        } else if (mat == 1) {
            Kt[tofs] = v;
        } else {
            Vt[tofs] = v;
        }
    }
}

// ---------------------------------------------------------------------------
// Kernel 2: Dpart[s][bh][k] = sum_{q in split s} 2^(Q'[q].K[k])
// grid (36 ktiles of 64, 16 bh, 4 qsplits), block 256 = 64 k x 4 waves.
// Each block sums 576 queries in 9 chunks of 64, staged via LDS w/ prefetch.
// ---------------------------------------------------------------------------
__global__ __launch_bounds__(256) void k_denom(
    const float* __restrict__ Qt, const float* __restrict__ Kt,
    float* __restrict__ Dpart)
{
    __shared__ float lQ[64][8];   // 2KB chunk of Q rows
    __shared__ float Dp[4][64];
    const int t  = threadIdx.x;
    const int bh = blockIdx.y;
    const int s  = blockIdx.z;
    const int k0 = blockIdx.x * 64;
    const int kk = t & 63, qs = t >> 6;

    const float4* krow = (const float4*)(Kt + ((long)bh * LL + k0 + kk) * 8);
    float4 ka = krow[0], kb = krow[1];

    const float4* qbase = (const float4*)(Qt + (long)bh * LL * 8) + (long)s * 1152;
    float4 pre;
    if (t < 128) pre = qbase[t];   // chunk 0 (128 float4 = 64 rows)

    float D = 0.f;
    for (int ch = 0; ch < 9; ++ch) {
        __syncthreads();                       // prior compute done, lQ free
        if (t < 128) ((float4*)lQ)[t] = pre;
        __syncthreads();                       // chunk visible
        if (t < 128 && ch + 1 < 9) pre = qbase[(ch + 1) * 128 + t];
        #pragma unroll
        for (int jj = 0; jj < 16; ++jj) {
            int j = qs * 16 + jj;              // wave-uniform -> LDS broadcast
            float4 qa = *(const float4*)&lQ[j][0];
            float4 qb = *(const float4*)&lQ[j][4];
            float2 s2 = f2mul(qa.x, qa.y, make_float2(ka.x, ka.y));
            s2 = f2fma(qa.z, qa.w, make_float2(ka.z, ka.w), s2);
            s2 = f2fma(qb.x, qb.y, make_float2(kb.x, kb.y), s2);
            s2 = f2fma(qb.z, qb.w, make_float2(kb.z, kb.w), s2);
            D += __builtin_amdgcn_exp2f(s2.x + s2.y);
        }
    }
    __syncthreads();
    Dp[qs][kk] = D;
    __syncthreads();
    if (t < 64) {
        float sum = Dp[0][t] + Dp[1][t] + Dp[2][t] + Dp[3][t];
        Dpart[(long)s * (16 * LL) + (long)bh * LL + k0 + t] = sum;
    }
}

// ---------------------------------------------------------------------------
// Kernel 3: ot_part[s][b][cv][q] = sum_{k in split s} V[k][cv]*rcpD[k]*2^(Q'.K)
// grid (72 qtiles of 32, 16 bh, 2 ksplits), block 256 = 32 q x 8 k-subranges.
// K/V chunks of 64 keys staged via LDS w/ register prefetch; rcpD folded from
// the 4 Dpart slabs at stage time.
// ---------------------------------------------------------------------------
__global__ __launch_bounds__(256) void k_av(
    const float* __restrict__ Qt, const float* __restrict__ Kt,
    const float* __restrict__ Vt, const float* __restrict__ Dpart,
    float* __restrict__ ot)
{
    __shared__ float lK[64][8];
    __shared__ float lV[64][8];
    __shared__ float lR[64];
    __shared__ float Op[8][32][9];   // pad 8->9: conflict-free reduce
    const int t  = threadIdx.x;
    const int bh = blockIdx.y;
    const int s  = blockIdx.z;
    const int b = bh >> 3, h = bh & 7;
    const int q0 = blockIdx.x * 32;
    const int qq = t & 31, ks = t >> 5;   // ks 0..7, two per wave (free 2-way)

    const float4* qrow = (const float4*)(Qt + ((long)bh * LL + q0 + qq) * 8);
    float4 qa = qrow[0], qb = qrow[1];

    const float4* kbase = (const float4*)(Kt + (long)bh * LL * 8) + (long)s * 2304;
    const float4* vbase = (const float4*)(Vt + (long)bh * LL * 8) + (long)s * 2304;
    const float* D0 = Dpart + (long)bh * LL + s * 1152;
    const float* D1 = D0 + 16 * LL;
    const float* D2 = D1 + 16 * LL;
    const float* D3 = D2 + 16 * LL;

    float4 pre = (t < 128) ? kbase[t] : vbase[t - 128];
    float r0, r1, r2, r3;
    if (t < 64) { r0 = D0[t]; r1 = D1[t]; r2 = D2[t]; r3 = D3[t]; }

    float2 o0 = {0.f, 0.f}, o1 = o0, o2 = o0, o3 = o0;
    for (int ch = 0; ch < 18; ++ch) {
        __syncthreads();
        if (t < 128) ((float4*)lK)[t] = pre;
        else         ((float4*)lV)[t - 128] = pre;
        if (t < 64)  lR[t] = 1.0f / (r0 + r1 + r2 + r3);
        __syncthreads();
        if (ch + 1 < 18) {
            pre = (t < 128) ? kbase[(ch + 1) * 128 + t]
                            : vbase[(ch + 1) * 128 + (t - 128)];
            if (t < 64) {
                int k = (ch + 1) * 64 + t;
                r0 = D0[k]; r1 = D1[k]; r2 = D2[k]; r3 = D3[k];
            }
        }
        #pragma unroll
        for (int jj = 0; jj < 8; ++jj) {
            int j = ks * 8 + jj;               // 2 distinct per wave: free
            float4 ka = *(const float4*)&lK[j][0];
            float4 kb = *(const float4*)&lK[j][4];
            float2 s2 = f2mul(ka.x, ka.y, make_float2(qa.x, qa.y));
            s2 = f2fma(ka.z, ka.w, make_float2(qa.z, qa.w), s2);
            s2 = f2fma(kb.x, kb.y, make_float2(qb.x, qb.y), s2);
            s2 = f2fma(kb.z, kb.w, make_float2(qb.z, qb.w), s2);
            float e = __builtin_amdgcn_exp2f(s2.x + s2.y) * lR[j];
            float4 va = *(const float4*)&lV[j][0];
            float4 vb = *(const float4*)&lV[j][4];
            float2 e2 = make_float2(e, e);
            o0 = f2fma(va.x, va.y, e2, o0);
            o1 = f2fma(va.z, va.w, e2, o1);
            o2 = f2fma(vb.x, vb.y, e2, o2);
            o3 = f2fma(vb.z, vb.w, e2, o3);
        }
    }
    __syncthreads();
    Op[ks][qq][0] = o0.x; Op[ks][qq][1] = o0.y;
    Op[ks][qq][2] = o1.x; Op[ks][qq][3] = o1.y;
    Op[ks][qq][4] = o2.x; Op[ks][qq][5] = o2.y;
    Op[ks][qq][6] = o3.x; Op[ks][qq][7] = o3.y;
    __syncthreads();
    {
        int q2 = t & 31, c = t >> 5;  // c 0..7
        float sum = 0.f;
        #pragma unroll
        for (int j2 = 0; j2 < 8; ++j2) sum += Op[j2][q2][c];
        float* osl = ot + (long)s * (2 * CCH * LL);
        osl[((long)b * CCH + h * 8 + c) * LL + q0 + q2] = sum;
    }
}

// ---------------------------------------------------------------------------
// Kernel 4: out[b][co][l] = sum_cv Wo[co][cv] * (ot0+ot1)[b][cv][l] + bo[co]
// grid (72 ltiles of 32, B), block 256 = 32 l x 8 cgroups of 8 co.
// ---------------------------------------------------------------------------
__global__ __launch_bounds__(256) void k_out(
    const float* __restrict__ ot, const float* __restrict__ Wo,
    const float* __restrict__ bo, float* __restrict__ out)
{
    __shared__ float os[64][32];
    __shared__ float wsm[64][64];
    const int t  = threadIdx.x;
    const int l0 = blockIdx.x * 32;
    const int b  = blockIdx.y;
    const float* ob0 = ot + (long)b * CCH * LL;
    const float* ob1 = ob0 + 2 * CCH * LL;

    #pragma unroll
    for (int p = 0; p < 2; ++p) {
        int flat = (p * 256 + t) * 4;
        int cv = flat >> 5, l = flat & 31;
        float4 a = *(const float4*)&ob0[(long)cv * LL + l0 + l];
        float4 bb = *(const float4*)&ob1[(long)cv * LL + l0 + l];
        a.x += bb.x; a.y += bb.y; a.z += bb.z; a.w += bb.w;
        *(float4*)&os[cv][l] = a;
    }
    #pragma unroll
    for (int p = 0; p < 4; ++p) {
        int flat = (p * 256 + t) * 4;
        int c = flat >> 6, l = flat & 63;
        *(float4*)&wsm[c][l] = *(const float4*)&Wo[flat];
    }
    __syncthreads();

    const int l  = t & 31;
    const int cg = t >> 5;  // 0..7
    float acc[8];
    #pragma unroll
    for (int j = 0; j < 8; ++j) acc[j] = 0.f;
    for (int cv = 0; cv < 64; ++cv) {
        float xv = os[cv][l];
        #pragma unroll
        for (int j = 0; j < 8; ++j) acc[j] = fmaf(wsm[cg * 8 + j][cv], xv, acc[j]);
    }
    #pragma unroll
    for (int j = 0; j < 8; ++j) {
        int co = cg * 8 + j;
        out[((long)b * CCH + co) * LL + l0 + l] = acc[j] + bo[co];
    }
}

// ---------------------------------------------------------------------------
extern "C" void kernel_launch(void* const* d_in, const int* in_sizes, int n_in,
                              void* d_out, int out_size, void* d_ws, size_t ws_size,
                              hipStream_t stream)
{
    const float* x  = (const float*)d_in[0];
    const float* Wq = (const float*)d_in[1];
    const float* bq = (const float*)d_in[2];
    const float* Wk = (const float*)d_in[3];
    const float* bk = (const float*)d_in[4];
    const float* Wv = (const float*)d_in[5];
    const float* bv = (const float*)d_in[6];
    const float* Wo = (const float*)d_in[7];
    const float* bo = (const float*)d_in[8];

    float* out  = (float*)d_out;          // [2][64][2304] = 294912 floats
    float* qout = out + 294912;           // second tuple output: scaled q

    float* wsf   = (float*)d_ws;          // 1,622,016 floats = 6.49 MB
    float* Qt    = wsf;                   // [16][2304][8], pre-scaled log2e*d^-.5
    float* Kt    = wsf + 294912;          // [16][2304][8]
    float* Vt    = wsf + 589824;          // [16][2304][8]
    float* Dpart = wsf + 884736;          // [4][16][2304]
    float* ot    = wsf + 1032192;         // [2][2][64][2304] (2 k-split slabs)

    k_qkv  <<<dim3(72, 2, 3),  256, 0, stream>>>(x, Wq, bq, Wk, bk, Wv, bv, qout, Qt, Kt, Vt);
    k_denom<<<dim3(36, 16, 4), 256, 0, stream>>>(Qt, Kt, Dpart);
    k_av   <<<dim3(72, 16, 2), 256, 0, stream>>>(Qt, Kt, Vt, Dpart, ot);
    k_out  <<<dim3(72, 2),     256, 0, stream>>>(ot, Wo, bo, out);
}

// Round 5
// 110.159 us; speedup vs baseline: 3.1069x; 1.4637x over previous
//
#include <hip/hip_runtime.h>

// Problem constants (B,C,H,W = 2,64,48,48; nh=8 -> d=8, L=2304)
#define LL   2304
#define CCH  64
#define NHD  8

static constexpr float QSCALE = 0.35355339059327373f;  // 8^-0.5
static constexpr float LOG2E  = 1.4426950408889634f;

typedef _Float16 half2_t  __attribute__((ext_vector_type(2)));
typedef _Float16 half4_t  __attribute__((ext_vector_type(4)));
typedef _Float16 half8_t  __attribute__((ext_vector_type(8)));
typedef float    float16_t __attribute__((ext_vector_type(16)));

__device__ __forceinline__ half2_t pk_f16(float a, float b) {
    return __builtin_bit_cast(half2_t, __builtin_amdgcn_cvt_pkrtz(a, b));
}

// v_mfma_f32_32x32x8_f16 lane maps (K=8):
//   A[m = lane&31][k = (lane>>5)*4 + j]   (half4 per lane)
//   B[k = (lane>>5)*4 + j][n = lane&31]
//   C/D: col = lane&31, row = (reg&3) + 8*(reg>>2) + 4*(lane>>5)
// => C reg-quad g of one MFMA == B operand (k-chunk [8g,8g+8)) of the next.

// ---------------------------------------------------------------------------
// Kernel 1: q/k/v = conv1x1(x, W*, b*).  Writes scaled q (f32) to d_out, and
// Q' (pre-scaled by log2e), K, V as f16 rows [bh][l][8] to workspace.
// grid (72 ltiles of 32, B, 3 mats), block 256 = 32 l x 8 heads.
// ---------------------------------------------------------------------------
__global__ __launch_bounds__(256) void k_qkv(
    const float* __restrict__ x,
    const float* __restrict__ Wq, const float* __restrict__ bq,
    const float* __restrict__ Wk, const float* __restrict__ bk,
    const float* __restrict__ Wv, const float* __restrict__ bv,
    float* __restrict__ qout,
    _Float16* __restrict__ Qt, _Float16* __restrict__ Kt, _Float16* __restrict__ Vt)
{
    __shared__ float xs[64][32];
    __shared__ float wsm[64][64];
    const int t   = threadIdx.x;
    const int l0  = blockIdx.x * 32;
    const int b   = blockIdx.y;
    const int mat = blockIdx.z;
    const float* W    = (mat == 0) ? Wq : (mat == 1 ? Wk : Wv);
    const float* bias = (mat == 0) ? bq : (mat == 1 ? bk : bv);
    const float* xb = x + (long)b * CCH * LL;

    #pragma unroll
    for (int p = 0; p < 2; ++p) {
        int flat = (p * 256 + t) * 4;
        int c = flat >> 5, l = flat & 31;
        *(float4*)&xs[c][l] = *(const float4*)&xb[(long)c * LL + l0 + l];
    }
    #pragma unroll
    for (int p = 0; p < 4; ++p) {
        int flat = (p * 256 + t) * 4;
        int c = flat >> 6, l = flat & 63;
        *(float4*)&wsm[c][l] = *(const float4*)&W[flat];
    }
    __syncthreads();

    const int l  = t & 31;
    const int cg = t >> 5;  // head 0..7
    float acc[8];
    #pragma unroll
    for (int j = 0; j < 8; ++j) acc[j] = 0.f;
    for (int cp = 0; cp < 64; ++cp) {
        float xv = xs[cp][l];
        #pragma unroll
        for (int j = 0; j < 8; ++j) acc[j] = fmaf(wsm[cg * 8 + j][cp], xv, acc[j]);
    }
    long row = (long)(b * NHD + cg) * LL + l0 + l;   // [bh][l] row, 8 f16 each
    if (mat == 0) {
        half8_t pq;
        #pragma unroll
        for (int j = 0; j < 8; ++j) {
            float qv = (acc[j] + bias[cg * 8 + j]) * QSCALE;
            qout[((long)b * CCH + cg * 8 + j) * LL + l0 + l] = qv;
            pq[j] = (_Float16)(qv * LOG2E);
        }
        *(half8_t*)(Qt + row * 8) = pq;
    } else if (mat == 1) {
        half8_t pk;
        #pragma unroll
        for (int j = 0; j < 8; ++j) pk[j] = (_Float16)(acc[j] + bias[cg * 8 + j]);
        *(half8_t*)(Kt + row * 8) = pk;
    } else {
        half8_t pv;
        #pragma unroll
        for (int j = 0; j < 8; ++j) pv[j] = (_Float16)(acc[j] + bias[cg * 8 + j]);
        *(half8_t*)(Vt + row * 8) = pv;
    }
}

// ---------------------------------------------------------------------------
// Kernel 2: D[k] = sum_q 2^(Q'[q].K[k]) via MFMA S^T tiles; epilogue writes
// V2[bh][c][k] = V[k][c] * 256/D[k]  (f16, transposed for k_av's A operand).
// grid (72 ktiles of 32, 16 bh), block 256 = 4 waves splitting q.
// ---------------------------------------------------------------------------
__global__ __launch_bounds__(256) void k_denom(
    const _Float16* __restrict__ Qt, const _Float16* __restrict__ Kt,
    const _Float16* __restrict__ Vt, _Float16* __restrict__ V2)
{
    __shared__ _Float16 lQ[2][256][4];   // 4KB: d-half-split Q chunk (256 rows)
    __shared__ float Dp[4][32];
    __shared__ float rDs[32];
    const int t    = threadIdx.x;
    const int bh   = blockIdx.y;
    const int k0   = blockIdx.x * 32;
    const int lane = t & 63, w = t >> 6;
    const int half = lane >> 5, l31 = lane & 31;

    // fixed A operand: K-tile rows k0..k0+31
    half4_t kA = *(const half4_t*)(Kt + ((long)bh * LL + k0 + l31) * 8 + half * 4);

    const float4* qbase = (const float4*)(Qt + (long)bh * LL * 8);  // 16B rows
    float4 pre = qbase[t];

    float16_t Dacc = {};
    for (int ch = 0; ch < 9; ++ch) {
        __syncthreads();
        *(float2*)&lQ[0][t][0] = make_float2(pre.x, pre.y);   // d 0..3
        *(float2*)&lQ[1][t][0] = make_float2(pre.z, pre.w);   // d 4..7
        __syncthreads();
        if (ch + 1 < 9) pre = qbase[(ch + 1) * 256 + t];
        #pragma unroll
        for (int T = 0; T < 2; ++T) {
            half4_t qB = *(const half4_t*)&lQ[half][(2 * w + T) * 32 + l31][0];
            float16_t S = __builtin_amdgcn_mfma_f32_32x32x8f16(kA, qB, (float16_t){}, 0, 0, 0);
            #pragma unroll
            for (int r = 0; r < 16; ++r) Dacc[r] += __builtin_amdgcn_exp2f(S[r]);
        }
    }
    // reduce over q-cols (lanes within each 32-half)
    #pragma unroll
    for (int r = 0; r < 16; ++r) {
        float v = Dacc[r];
        v += __shfl_xor(v, 1);  v += __shfl_xor(v, 2);  v += __shfl_xor(v, 4);
        v += __shfl_xor(v, 8);  v += __shfl_xor(v, 16);
        Dacc[r] = v;
    }
    if (l31 == 0) {
        #pragma unroll
        for (int r = 0; r < 16; ++r) {
            int row = (r & 3) + 8 * (r >> 2) + 4 * half;
            Dp[w][row] = Dacc[r];
        }
    }
    __syncthreads();
    if (t < 32) rDs[t] = 256.0f / (Dp[0][t] + Dp[1][t] + Dp[2][t] + Dp[3][t]);
    __syncthreads();
    {   // V2[bh][c][k0+kk] = V[k0+kk][c] * rDs[kk]
        int kk = t >> 3, c = t & 7;
        float v = (float)Vt[((long)bh * LL + k0 + kk) * 8 + c];
        V2[((long)bh * 8 + c) * LL + k0 + kk] = (_Float16)(v * rDs[kk]);
    }
}

// ---------------------------------------------------------------------------
// Kernel 3: O'[c,q] = sum_k V2[c,k] * 2^(Q'[q].K[k]); S^T C-regs feed PV MFMA
// as B operand quad-by-quad (no LDS roundtrip for P).  4 k-splits -> 4 slabs.
// grid (18 q-blocks of 128, 16 bh, 4 ksplits), block 256 = 4 waves x 32 q.
// ---------------------------------------------------------------------------
__global__ __launch_bounds__(256) void k_av(
    const _Float16* __restrict__ Qt, const _Float16* __restrict__ Kt,
    const _Float16* __restrict__ V2, float* __restrict__ ot)
{
    __shared__ _Float16 lK[2][64][4];    // 1KB: d-half-split K chunk (64 rows)
    __shared__ _Float16 lVt[8][72];      // V2 chunk [8c][64k], padded to 72
    const int t    = threadIdx.x;
    const int bh   = blockIdx.y;
    const int s    = blockIdx.z;
    const int b = bh >> 3, h = bh & 7;
    const int lane = t & 63, w = t >> 6;
    const int half = lane >> 5, l31 = lane & 31;
    const int q0   = blockIdx.x * 128 + w * 32;

    // fixed B operand: Q-tile cols q0..q0+31
    half4_t qB = *(const half4_t*)(Qt + ((long)bh * LL + q0 + l31) * 8 + half * 4);

    const long ks0 = (long)s * 576;
    const float4*    kbase = (const float4*)(Kt + ((long)bh * LL + ks0) * 8);
    const _Float16*  vbase = V2 + (long)bh * 8 * LL + ks0;

    float4 preK, preV;
    if (t < 64) preK = kbase[t];
    else if (t < 128) {
        int c = (t - 64) >> 3, j8 = (t - 64) & 7;
        preV = *(const float4*)(vbase + (long)c * LL + j8 * 8);
    }

    float16_t O = {};
    for (int ch = 0; ch < 9; ++ch) {
        __syncthreads();
        if (t < 64) {
            *(float2*)&lK[0][t][0] = make_float2(preK.x, preK.y);
            *(float2*)&lK[1][t][0] = make_float2(preK.z, preK.w);
        } else if (t < 128) {
            int c = (t - 64) >> 3, j8 = (t - 64) & 7;
            *(float4*)&lVt[c][j8 * 8] = preV;
        }
        __syncthreads();
        if (ch + 1 < 9) {
            if (t < 64) preK = kbase[(ch + 1) * 64 + t];
            else if (t < 128) {
                int c = (t - 64) >> 3, j8 = (t - 64) & 7;
                preV = *(const float4*)(vbase + (long)c * LL + (ch + 1) * 64 + j8 * 8);
            }
        }
        const int cl = l31 & 7;   // lanes 8..31 duplicate c rows (D rows >=8 unused)
        #pragma unroll
        for (int T = 0; T < 2; ++T) {
            int kb = T * 32;
            half4_t kA = *(const half4_t*)&lK[half][kb + l31][0];
            float16_t S = __builtin_amdgcn_mfma_f32_32x32x8f16(kA, qB, (float16_t){}, 0, 0, 0);
            #pragma unroll
            for (int g = 0; g < 4; ++g) {
                half2_t p0 = pk_f16(__builtin_amdgcn_exp2f(S[4 * g + 0]),
                                    __builtin_amdgcn_exp2f(S[4 * g + 1]));
                half2_t p1 = pk_f16(__builtin_amdgcn_exp2f(S[4 * g + 2]),
                                    __builtin_amdgcn_exp2f(S[4 * g + 3]));
                half4_t pB = __builtin_shufflevector(p0, p1, 0, 1, 2, 3);
                half4_t vA = *(const half4_t*)&lVt[cl][kb + g * 8 + half * 4];
                O = __builtin_amdgcn_mfma_f32_32x32x8f16(vA, pB, O, 0, 0, 0);
            }
        }
    }
    // rows c<8 live in regs 0..3: c = r + 4*half; col q = l31
    float* otb = ot + (long)s * (2 * CCH * LL) + ((long)b * CCH + h * 8) * LL;
    #pragma unroll
    for (int r = 0; r < 4; ++r) {
        int c = r + 4 * half;
        otb[(long)c * LL + q0 + l31] = O[r] * (1.0f / 256.0f);
    }
}

// ---------------------------------------------------------------------------
// Kernel 4: out = Wo . (sum of 4 ot slabs) + bo
// grid (72 ltiles of 32, B), block 256 = 32 l x 8 cgroups of 8 co.
// ---------------------------------------------------------------------------
__global__ __launch_bounds__(256) void k_out(
    const float* __restrict__ ot, const float* __restrict__ Wo,
    const float* __restrict__ bo, float* __restrict__ out)
{
    __shared__ float os[64][32];
    __shared__ float wsm[64][64];
    const int t  = threadIdx.x;
    const int l0 = blockIdx.x * 32;
    const int b  = blockIdx.y;
    const long SLAB = 2 * CCH * (long)LL;
    const float* ob = ot + (long)b * CCH * LL;

    #pragma unroll
    for (int p = 0; p < 2; ++p) {
        int flat = (p * 256 + t) * 4;
        int cv = flat >> 5, l = flat & 31;
        long off = (long)cv * LL + l0 + l;
        float4 a = *(const float4*)&ob[off];
        #pragma unroll
        for (int s = 1; s < 4; ++s) {
            float4 bb = *(const float4*)&ob[s * SLAB + off];
            a.x += bb.x; a.y += bb.y; a.z += bb.z; a.w += bb.w;
        }
        *(float4*)&os[cv][l] = a;
    }
    #pragma unroll
    for (int p = 0; p < 4; ++p) {
        int flat = (p * 256 + t) * 4;
        int c = flat >> 6, l = flat & 63;
        *(float4*)&wsm[c][l] = *(const float4*)&Wo[flat];
    }
    __syncthreads();

    const int l  = t & 31;
    const int cg = t >> 5;
    float acc[8];
    #pragma unroll
    for (int j = 0; j < 8; ++j) acc[j] = 0.f;
    for (int cv = 0; cv < 64; ++cv) {
        float xv = os[cv][l];
        #pragma unroll
        for (int j = 0; j < 8; ++j) acc[j] = fmaf(wsm[cg * 8 + j][cv], xv, acc[j]);
    }
    #pragma unroll
    for (int j = 0; j < 8; ++j) {
        int co = cg * 8 + j;
        out[((long)b * CCH + co) * LL + l0 + l] = acc[j] + bo[co];
    }
}

// ---------------------------------------------------------------------------
extern "C" void kernel_launch(void* const* d_in, const int* in_sizes, int n_in,
                              void* d_out, int out_size, void* d_ws, size_t ws_size,
                              hipStream_t stream)
{
    const float* x  = (const float*)d_in[0];
    const float* Wq = (const float*)d_in[1];
    const float* bq = (const float*)d_in[2];
    const float* Wk = (const float*)d_in[3];
    const float* bk = (const float*)d_in[4];
    const float* Wv = (const float*)d_in[5];
    const float* bv = (const float*)d_in[6];
    const float* Wo = (const float*)d_in[7];
    const float* bo = (const float*)d_in[8];

    float* out  = (float*)d_out;          // [2][64][2304]
    float* qout = out + 294912;           // second tuple output: scaled q

    // ws: 4 f16 buffers (576KB ea) + 4 f32 ot slabs (4.7MB) = 7.08 MB
    _Float16* Qt = (_Float16*)d_ws;       // [16][2304][8] f16, * log2e*d^-0.5
    _Float16* Kt = Qt + 294912;           // [16][2304][8] f16
    _Float16* Vt = Kt + 294912;           // [16][2304][8] f16 (raw V)
    _Float16* V2 = Vt + 294912;           // [16][8][2304] f16 = V^T * 256/D
    float*    ot = (float*)(V2 + 294912); // [4][2][64][2304] f32 partial slabs

    k_qkv  <<<dim3(72, 2, 3),  256, 0, stream>>>(x, Wq, bq, Wk, bk, Wv, bv, qout, Qt, Kt, Vt);
    k_denom<<<dim3(72, 16),    256, 0, stream>>>(Qt, Kt, Vt, V2);
    k_av   <<<dim3(18, 16, 4), 256, 0, stream>>>(Qt, Kt, V2, ot);
    k_out  <<<dim3(72, 2),     256, 0, stream>>>(ot, Wo, bo, out);
}